// Round 6
// baseline (138.627 us; speedup 1.0000x reference)
//
#include <hip/hip_runtime.h>
#include <hip/hip_bf16.h>
#include <hip/hip_cooperative_groups.h>

namespace cg = cooperative_groups;

// Problem constants (from reference): B=8, S=1024, E=64, H=8, DK=8
#define BB 8
#define SS 1024
#define EE 64
#define HH 8
#define DKW 8

typedef __hip_bfloat16 bf16;
typedef unsigned short u16;
typedef _Float16 half8v __attribute__((ext_vector_type(8)));
typedef float floatx4 __attribute__((ext_vector_type(4)));

#define MFMA16(a, b, c) __builtin_amdgcn_mfma_f32_16x16x32_f16(a, b, c, 0, 0, 0)

// d_ws layout: [0,1MB) projH fp16 [B][S][E]; [1MB,2MB) projT fp16 [B][E][S]
#define OFF_PROJT ((size_t)BB * SS * EE * 2)

// ---------------------------------------------------------------------------
// Block-uniform dtype self-detection (R4/R5-proven): if `base` really holds
// float32, even-indexed u16s are random f32 mantissa bits -> ~48% decode (as
// bf16) to |v| >= 32; genuine bf16 N(0,1) -> ~0. Deterministic per buffer.
template <int NT>
__device__ __forceinline__ bool detect_f32(const u16* __restrict__ base,
                                           int tid, int* red) {
    int cnt = 0;
    for (int i = tid; i < 2048; i += NT) {
        u16 u = base[i * 2];
        int ex = (u >> 7) & 0xFF;
        cnt += (ex >= 0x84) ? 1 : 0;
    }
#pragma unroll
    for (int off = 32; off > 0; off >>= 1) cnt += __shfl_xor(cnt, off, 64);
    if ((tid & 63) == 0) red[tid >> 6] = cnt;
    __syncthreads();
    int tot = 0;
#pragma unroll
    for (int w = 0; w < NT / 64; ++w) tot += red[w];
    return tot > 64;
}

// ---------------------------------------------------------------------------
// Analytic quantum projection (R0 derivation, verified R2-R5):
//   Z_0 = prod_{j=1..7} cos(theta_j);  Z_w = prod_{j=0..w} cos(theta_j)
__device__ __forceinline__ void proj_compute(const void* x, const void* phi,
                                             bool f32, int m, float* z) {
    int h = m & (HH - 1);
    float th[DKW];
    if (f32) {
        const float4* xp = (const float4*)((const float*)x + (size_t)m * DKW);
        const float4* pp = (const float4*)((const float*)phi + h * DKW);
        float4 x0 = xp[0], x1 = xp[1];
        float4 p0 = pp[0], p1 = pp[1];
        th[0] = x0.x + p0.x; th[1] = x0.y + p0.y; th[2] = x0.z + p0.z; th[3] = x0.w + p0.w;
        th[4] = x1.x + p1.x; th[5] = x1.y + p1.y; th[6] = x1.z + p1.z; th[7] = x1.w + p1.w;
    } else {
        union { uint4 u; bf16 hv[8]; } xu, pu;
        xu.u = *(const uint4*)((const bf16*)x + (size_t)m * DKW);
        pu.u = *(const uint4*)((const bf16*)phi + (size_t)h * DKW);
#pragma unroll
        for (int j = 0; j < DKW; ++j)
            th[j] = __bfloat162float(xu.hv[j]) + __bfloat162float(pu.hv[j]);
    }
    float c[DKW];
#pragma unroll
    for (int j = 0; j < DKW; ++j) c[j] = __cosf(th[j]);
    float suf = c[1];
#pragma unroll
    for (int j = 2; j < DKW; ++j) suf *= c[j];
    z[0] = suf;
    float pre = c[0];
#pragma unroll
    for (int w = 1; w < DKW; ++w) { pre *= c[w]; z[w] = pre; }
}

// Stile: flat 16x1024 fp16, XOR-swizzled; phase-3 b128 A-reads 2 lanes/bank.
__device__ __forceinline__ int sidx(int row, int colblk) {
    return row * 1024 + ((colblk ^ (row & 7)) << 3);
}

// ---------------------------------------------------------------------------
// MEGA kernel (cooperative): phase A computes proj for 128 m's per block,
// grid.sync(), phase B = R5's fused attention (16 q-rows/block).
// Grid 512 x 512 thr, ~42 KB LDS, launch_bounds(512,4) -> 2 blocks/CU.
__global__ __launch_bounds__(512, 4) void mega_kernel(const void* __restrict__ x,
                                                      const void* __restrict__ phi,
                                                      const void* __restrict__ Wp,
                                                      const void* __restrict__ biasp,
                                                      void* __restrict__ outp,
                                                      _Float16* __restrict__ projH,
                                                      _Float16* __restrict__ projT) {
    __shared__ _Float16 Stile[16 * 1024];          // 32 KB, swizzled
    __shared__ float    pacc[4][16][17];
    __shared__ _Float16 ctx_lds[16][72];
    __shared__ _Float16 zt[EE][24];
    __shared__ float    rowsum[16];
    __shared__ int      redd[8];

    const int tid = threadIdx.x;
    const int wave = tid >> 6, lane = tid & 63;
    const int lr = lane & 15, quad = lane >> 4;
    const int blk = blockIdx.x;

    // one detect on x decides the whole pipeline's dtype (all buffers share it)
    const bool f32 = detect_f32<512>((const u16*)x, tid, redd);

    // ---- phase A: projection for m in [blk*128, blk*128+128)
    {
        if (tid < 128) {
            int m = blk * 128 + tid;
            float z[DKW];
            proj_compute(x, phi, f32, m, z);
            union { half8v v; _Float16 h[8]; } o;
#pragma unroll
            for (int j = 0; j < DKW; ++j) o.h[j] = (_Float16)z[j];
            *(half8v*)(projH + (size_t)m * DKW) = o.v;
            int h = m & (HH - 1), sl = tid >> 3;
#pragma unroll
            for (int j = 0; j < DKW; ++j) zt[h * DKW + j][sl] = o.h[j];
        }
        __syncthreads();
        if (tid < 128) {
            int pb = blk >> 6;
            int s0 = (blk & 63) * 16;
            int row = tid >> 1, ch = tid & 1;
            half8v vv = *(const half8v*)(&zt[row][ch * 8]);
            *(half8v*)(projT + ((size_t)(pb * EE + row)) * SS + s0 + ch * 8) = vv;
        }
    }
    cg::this_grid().sync();

    // ---- phase B: fused attention for 16 q-rows
    const int b = blk >> 6;
    const int m0 = (blk & 63) * 16;
    const _Float16* Pb = projH + (size_t)b * SS * EE;
    const float scale = 0.35355339059327373f;  // 1/sqrt(DK)

    // phase 1: S = scale * Q . K^T  -> Stile (each wave: 128 cols)
    {
        const _Float16* arow = Pb + (size_t)(m0 + lr) * EE;
        half8v a0 = *(const half8v*)(arow + quad * 8);
        half8v a1 = *(const half8v*)(arow + 32 + quad * 8);
#pragma unroll 4
        for (int c = 0; c < 8; ++c) {
            int n = wave * 128 + c * 16;
            const _Float16* brow = Pb + (size_t)(n + lr) * EE;
            half8v b0 = *(const half8v*)(brow + quad * 8);
            half8v b1 = *(const half8v*)(brow + 32 + quad * 8);
            floatx4 acc = {0.f, 0.f, 0.f, 0.f};
            acc = MFMA16(a0, b0, acc);
            acc = MFMA16(a1, b1, acc);
#pragma unroll
            for (int r = 0; r < 4; ++r) {
                int row = quad * 4 + r, col = n + lr;
                Stile[sidx(row, col >> 3) + (col & 7)] = (_Float16)(acc[r] * scale);
            }
        }
    }
    __syncthreads();

    // phase 2: exact softmax (swizzle is a within-row permutation)
    {
        const int row = tid >> 5, seg = tid & 31;
        half8v hv[4];
#pragma unroll
        for (int i = 0; i < 4; ++i)
            hv[i] = *(const half8v*)(&Stile[sidx(row, i * 32 + seg)]);
        float mloc = -1e30f;
#pragma unroll
        for (int i = 0; i < 4; ++i)
#pragma unroll
            for (int j = 0; j < 8; ++j) mloc = fmaxf(mloc, (float)hv[i][j]);
#pragma unroll
        for (int off = 16; off > 0; off >>= 1)
            mloc = fmaxf(mloc, __shfl_xor(mloc, off, 64));
        float lsum = 0.f;
#pragma unroll
        for (int i = 0; i < 4; ++i) {
#pragma unroll
            for (int j = 0; j < 8; ++j) {
                float e = __expf((float)hv[i][j] - mloc);
                lsum += e;
                hv[i][j] = (_Float16)(e * 256.f);  // prescale vs fp16 denormals
            }
        }
#pragma unroll
        for (int off = 16; off > 0; off >>= 1)
            lsum += __shfl_xor(lsum, off, 64);
        if (seg == 0) rowsum[row] = lsum;
#pragma unroll
        for (int i = 0; i < 4; ++i)
            *(half8v*)(&Stile[sidx(row, i * 32 + seg)]) = hv[i];
    }
    __syncthreads();

    // phase 3: ctx = P . V; wave = (khalf) x (colg); K split 2-way
    const int khalf = wave >> 2, colg = wave & 3;
    floatx4 accT;
    {
        const _Float16* vrow = projT + ((size_t)(b * EE + colg * 16 + lr)) * SS
                               + khalf * 512;
        const int sbase = khalf * 64;
        floatx4 acc0 = {0.f, 0.f, 0.f, 0.f};
        floatx4 acc1 = {0.f, 0.f, 0.f, 0.f};
#pragma unroll 4
        for (int t = 0; t < 512; t += 64) {
            half8v aA = *(const half8v*)(&Stile[sidx(lr, sbase + (t >> 3) + quad)]);
            half8v vA = *(const half8v*)(vrow + t + quad * 8);
            half8v aB = *(const half8v*)(&Stile[sidx(lr, sbase + ((t + 32) >> 3) + quad)]);
            half8v vB = *(const half8v*)(vrow + t + 32 + quad * 8);
            acc0 = MFMA16(aA, vA, acc0);
            acc1 = MFMA16(aB, vB, acc1);
        }
        accT = acc0 + acc1;
    }
    if (khalf == 1) {
#pragma unroll
        for (int r = 0; r < 4; ++r) pacc[colg][quad * 4 + r][lr] = accT[r];
    }
    __syncthreads();
    if (khalf == 0) {
#pragma unroll
        for (int r = 0; r < 4; ++r) {
            int row_l = quad * 4 + r;
            float inv = 1.0f / (256.0f * rowsum[row_l]);
            ctx_lds[row_l][colg * 16 + lr] =
                (_Float16)((accT[r] + pacc[colg][row_l][lr]) * inv);
        }
    }
    __syncthreads();

    // phase 4: out = ctx @ W^T + bias (waves 0-3)
    if (wave < 4) {
        const int o = wave * 16 + lr;
        half8v ca0 = *(const half8v*)(&ctx_lds[lr][quad * 8]);
        half8v ca1 = *(const half8v*)(&ctx_lds[lr][32 + quad * 8]);
        half8v wb0, wb1;
        if (f32) {
            const float* wr = (const float*)Wp + (size_t)o * EE;
            union { half8v v; _Float16 h[8]; } w0, w1;
#pragma unroll
            for (int j = 0; j < 8; ++j) {
                w0.h[j] = (_Float16)wr[quad * 8 + j];
                w1.h[j] = (_Float16)wr[32 + quad * 8 + j];
            }
            wb0 = w0.v; wb1 = w1.v;
        } else {
            const bf16* wr = (const bf16*)Wp + (size_t)o * EE;
            union { uint4 u; bf16 hv[8]; } r0, r1;
            r0.u = *(const uint4*)(wr + quad * 8);
            r1.u = *(const uint4*)(wr + 32 + quad * 8);
            union { half8v v; _Float16 h[8]; } w0, w1;
#pragma unroll
            for (int j = 0; j < 8; ++j) {
                w0.h[j] = (_Float16)__bfloat162float(r0.hv[j]);
                w1.h[j] = (_Float16)__bfloat162float(r1.hv[j]);
            }
            wb0 = w0.v; wb1 = w1.v;
        }
        floatx4 oacc = {0.f, 0.f, 0.f, 0.f};
        oacc = MFMA16(ca0, wb0, oacc);
        oacc = MFMA16(ca1, wb1, oacc);

        float bo = f32 ? ((const float*)biasp)[o]
                       : __bfloat162float(((const bf16*)biasp)[o]);
#pragma unroll
        for (int r = 0; r < 4; ++r) {
            size_t oi = ((size_t)b * SS + m0 + quad * 4 + r) * EE + o;
            float val = oacc[r] + bo;
            if (f32) ((float*)outp)[oi] = val;
            else     ((bf16*)outp)[oi] = __float2bfloat16(val);
        }
    }
}

// ---------------------------------------------------------------------------
// Fallback path: R5's proven 2-kernel pipeline (if cooperative launch fails).
__global__ __launch_bounds__(256) void proj_f16_kernel(const void* __restrict__ x,
                                                       const void* __restrict__ phi,
                                                       _Float16* __restrict__ projH,
                                                       _Float16* __restrict__ projT) {
    __shared__ int redd[4];
    __shared__ _Float16 zt[EE][40];
    const int tid = threadIdx.x;
    const bool f32 = detect_f32<256>((const u16*)x, tid, redd);

    const int m = blockIdx.x * 256 + tid;
    float z[DKW];
    proj_compute(x, phi, f32, m, z);

    union { half8v v; _Float16 h[8]; } o;
#pragma unroll
    for (int j = 0; j < DKW; ++j) o.h[j] = (_Float16)z[j];
    *(half8v*)(projH + (size_t)m * DKW) = o.v;

    const int h = m & (HH - 1);
    const int sl = (tid >> 3) & 31;
#pragma unroll
    for (int j = 0; j < DKW; ++j) zt[h * DKW + j][sl] = o.h[j];
    __syncthreads();

    const int b = blockIdx.x >> 5;
    const int s0 = (blockIdx.x * 32) & (SS - 1);
    const int row = tid >> 2, ch = tid & 3;
    half8v vv = *(const half8v*)(&zt[row][ch * 8]);
    *(half8v*)(projT + ((size_t)(b * EE + row)) * SS + s0 + ch * 8) = vv;
}

__global__ __launch_bounds__(512) void fused_attn(const _Float16* __restrict__ projH,
                                                  const _Float16* __restrict__ projT,
                                                  const void* __restrict__ Wp,
                                                  const void* __restrict__ biasp,
                                                  void* __restrict__ outp) {
    __shared__ _Float16 Stile[16 * 1024];
    __shared__ float    pacc[4][16][17];
    __shared__ _Float16 ctx_lds[16][72];
    __shared__ float    rowsum[16];
    __shared__ int      redd[8];

    const int tid = threadIdx.x;
    const int wave = tid >> 6, lane = tid & 63;
    const int lr = lane & 15, quad = lane >> 4;
    const int b = blockIdx.y;
    const int m0 = blockIdx.x * 16;

    const bool f32 = detect_f32<512>((const u16*)Wp, tid, redd);
    const _Float16* Pb = projH + (size_t)b * SS * EE;
    const float scale = 0.35355339059327373f;

    {
        const _Float16* arow = Pb + (size_t)(m0 + lr) * EE;
        half8v a0 = *(const half8v*)(arow + quad * 8);
        half8v a1 = *(const half8v*)(arow + 32 + quad * 8);
#pragma unroll 4
        for (int c = 0; c < 8; ++c) {
            int n = wave * 128 + c * 16;
            const _Float16* brow = Pb + (size_t)(n + lr) * EE;
            half8v b0 = *(const half8v*)(brow + quad * 8);
            half8v b1 = *(const half8v*)(brow + 32 + quad * 8);
            floatx4 acc = {0.f, 0.f, 0.f, 0.f};
            acc = MFMA16(a0, b0, acc);
            acc = MFMA16(a1, b1, acc);
#pragma unroll
            for (int r = 0; r < 4; ++r) {
                int row = quad * 4 + r, col = n + lr;
                Stile[sidx(row, col >> 3) + (col & 7)] = (_Float16)(acc[r] * scale);
            }
        }
    }
    __syncthreads();
    {
        const int row = tid >> 5, seg = tid & 31;
        half8v hv[4];
#pragma unroll
        for (int i = 0; i < 4; ++i)
            hv[i] = *(const half8v*)(&Stile[sidx(row, i * 32 + seg)]);
        float mloc = -1e30f;
#pragma unroll
        for (int i = 0; i < 4; ++i)
#pragma unroll
            for (int j = 0; j < 8; ++j) mloc = fmaxf(mloc, (float)hv[i][j]);
#pragma unroll
        for (int off = 16; off > 0; off >>= 1)
            mloc = fmaxf(mloc, __shfl_xor(mloc, off, 64));
        float lsum = 0.f;
#pragma unroll
        for (int i = 0; i < 4; ++i) {
#pragma unroll
            for (int j = 0; j < 8; ++j) {
                float e = __expf((float)hv[i][j] - mloc);
                lsum += e;
                hv[i][j] = (_Float16)(e * 256.f);
            }
        }
#pragma unroll
        for (int off = 16; off > 0; off >>= 1)
            lsum += __shfl_xor(lsum, off, 64);
        if (seg == 0) rowsum[row] = lsum;
#pragma unroll
        for (int i = 0; i < 4; ++i)
            *(half8v*)(&Stile[sidx(row, i * 32 + seg)]) = hv[i];
    }
    __syncthreads();

    const int khalf = wave >> 2, colg = wave & 3;
    floatx4 accT;
    {
        const _Float16* vrow = projT + ((size_t)(b * EE + colg * 16 + lr)) * SS
                               + khalf * 512;
        const int sbase = khalf * 64;
        floatx4 acc0 = {0.f, 0.f, 0.f, 0.f};
        floatx4 acc1 = {0.f, 0.f, 0.f, 0.f};
#pragma unroll 4
        for (int t = 0; t < 512; t += 64) {
            half8v aA = *(const half8v*)(&Stile[sidx(lr, sbase + (t >> 3) + quad)]);
            half8v vA = *(const half8v*)(vrow + t + quad * 8);
            half8v aB = *(const half8v*)(&Stile[sidx(lr, sbase + ((t + 32) >> 3) + quad)]);
            half8v vB = *(const half8v*)(vrow + t + 32 + quad * 8);
            acc0 = MFMA16(aA, vA, acc0);
            acc1 = MFMA16(aB, vB, acc1);
        }
        accT = acc0 + acc1;
    }
    if (khalf == 1) {
#pragma unroll
        for (int r = 0; r < 4; ++r) pacc[colg][quad * 4 + r][lr] = accT[r];
    }
    __syncthreads();
    if (khalf == 0) {
#pragma unroll
        for (int r = 0; r < 4; ++r) {
            int row_l = quad * 4 + r;
            float inv = 1.0f / (256.0f * rowsum[row_l]);
            ctx_lds[row_l][colg * 16 + lr] =
                (_Float16)((accT[r] + pacc[colg][row_l][lr]) * inv);
        }
    }
    __syncthreads();

    if (wave < 4) {
        const int o = wave * 16 + lr;
        half8v ca0 = *(const half8v*)(&ctx_lds[lr][quad * 8]);
        half8v ca1 = *(const half8v*)(&ctx_lds[lr][32 + quad * 8]);
        half8v wb0, wb1;
        if (f32) {
            const float* wr = (const float*)Wp + (size_t)o * EE;
            union { half8v v; _Float16 h[8]; } w0, w1;
#pragma unroll
            for (int j = 0; j < 8; ++j) {
                w0.h[j] = (_Float16)wr[quad * 8 + j];
                w1.h[j] = (_Float16)wr[32 + quad * 8 + j];
            }
            wb0 = w0.v; wb1 = w1.v;
        } else {
            const bf16* wr = (const bf16*)Wp + (size_t)o * EE;
            union { uint4 u; bf16 hv[8]; } r0, r1;
            r0.u = *(const uint4*)(wr + quad * 8);
            r1.u = *(const uint4*)(wr + 32 + quad * 8);
            union { half8v v; _Float16 h[8]; } w0, w1;
#pragma unroll
            for (int j = 0; j < 8; ++j) {
                w0.h[j] = (_Float16)__bfloat162float(r0.hv[j]);
                w1.h[j] = (_Float16)__bfloat162float(r1.hv[j]);
            }
            wb0 = w0.v; wb1 = w1.v;
        }
        floatx4 oacc = {0.f, 0.f, 0.f, 0.f};
        oacc = MFMA16(ca0, wb0, oacc);
        oacc = MFMA16(ca1, wb1, oacc);

        float bo = f32 ? ((const float*)biasp)[o]
                       : __bfloat162float(((const bf16*)biasp)[o]);
#pragma unroll
        for (int r = 0; r < 4; ++r) {
            size_t oi = ((size_t)b * SS + m0 + quad * 4 + r) * EE + o;
            float val = oacc[r] + bo;
            if (f32) ((float*)outp)[oi] = val;
            else     ((bf16*)outp)[oi] = __float2bfloat16(val);
        }
    }
}

// ---------------------------------------------------------------------------
extern "C" void kernel_launch(void* const* d_in, const int* in_sizes, int n_in,
                              void* d_out, int out_size, void* d_ws, size_t ws_size,
                              hipStream_t stream) {
    const void* x    = d_in[0];
    const void* phi  = d_in[1];
    const void* W    = d_in[2];
    const void* bias = d_in[3];
    void* outp = d_out;

    _Float16* projH = (_Float16*)d_ws;
    _Float16* projT = (_Float16*)((char*)d_ws + OFF_PROJT);

    void* args[] = {(void*)&x, (void*)&phi, (void*)&W, (void*)&bias,
                    (void*)&outp, (void*)&projH, (void*)&projT};
    hipError_t err = hipLaunchCooperativeKernel(
        reinterpret_cast<void*>(mega_kernel), dim3(512), dim3(512), args, 0, stream);

    if (err != hipSuccess) {
        // fallback: proven R5 two-kernel path
        proj_f16_kernel<<<dim3(BB * SS * HH / 256), dim3(256), 0, stream>>>(
            x, phi, projH, projT);
        fused_attn<<<dim3(SS / 16, BB), dim3(512), 0, stream>>>(
            projH, projT, W, bias, d_out);
    }
}

// Round 7
// 86.428 us; speedup vs baseline: 1.6040x; 1.6040x over previous
//
#include <hip/hip_runtime.h>
#include <hip/hip_bf16.h>

// Problem constants (from reference): B=8, S=1024, E=64, H=8, DK=8
#define BB 8
#define SS 1024
#define EE 64
#define HH 8
#define DKW 8

typedef __hip_bfloat16 bf16;
typedef unsigned short u16;
typedef _Float16 half8v __attribute__((ext_vector_type(8)));
typedef float floatx4 __attribute__((ext_vector_type(4)));

#define MFMA16(a, b, c) __builtin_amdgcn_mfma_f32_16x16x32_f16(a, b, c, 0, 0, 0)

// d_ws layout: [0,1MB) projH fp16 [B][S][E]; [1MB,2MB) projT fp16 [B][E][S]
#define OFF_PROJT ((size_t)BB * SS * EE * 2)

// ---------------------------------------------------------------------------
// Block-uniform dtype self-detection (R4-R6 proven): if `base` really holds
// float32, even-indexed u16s are random f32 mantissa bits -> ~48% decode (as
// bf16) to |v| >= 32; genuine bf16 N(0,1) -> ~0. Deterministic per buffer.
template <int NT>
__device__ __forceinline__ bool detect_f32(const u16* __restrict__ base,
                                           int tid, int* red) {
    int cnt = 0;
    for (int i = tid; i < 2048; i += NT) {
        u16 u = base[i * 2];
        int ex = (u >> 7) & 0xFF;
        cnt += (ex >= 0x84) ? 1 : 0;
    }
#pragma unroll
    for (int off = 32; off > 0; off >>= 1) cnt += __shfl_xor(cnt, off, 64);
    if ((tid & 63) == 0) red[tid >> 6] = cnt;
    __syncthreads();
    int tot = 0;
#pragma unroll
    for (int w = 0; w < NT / 64; ++w) tot += red[w];
    return tot > 64;
}

// ---------------------------------------------------------------------------
// Analytic quantum projection (R0 derivation, verified R2-R6):
//   Z_0 = prod_{j=1..7} cos(theta_j);  Z_w = prod_{j=0..w} cos(theta_j)
__device__ __forceinline__ void proj_compute(const void* x, const void* phi,
                                             bool f32, int m, float* z) {
    int h = m & (HH - 1);
    float th[DKW];
    if (f32) {
        const float4* xp = (const float4*)((const float*)x + (size_t)m * DKW);
        const float4* pp = (const float4*)((const float*)phi + h * DKW);
        float4 x0 = xp[0], x1 = xp[1];
        float4 p0 = pp[0], p1 = pp[1];
        th[0] = x0.x + p0.x; th[1] = x0.y + p0.y; th[2] = x0.z + p0.z; th[3] = x0.w + p0.w;
        th[4] = x1.x + p1.x; th[5] = x1.y + p1.y; th[6] = x1.z + p1.z; th[7] = x1.w + p1.w;
    } else {
        union { uint4 u; bf16 hv[8]; } xu, pu;
        xu.u = *(const uint4*)((const bf16*)x + (size_t)m * DKW);
        pu.u = *(const uint4*)((const bf16*)phi + (size_t)h * DKW);
#pragma unroll
        for (int j = 0; j < DKW; ++j)
            th[j] = __bfloat162float(xu.hv[j]) + __bfloat162float(pu.hv[j]);
    }
    float c[DKW];
#pragma unroll
    for (int j = 0; j < DKW; ++j) c[j] = __cosf(th[j]);
    float suf = c[1];
#pragma unroll
    for (int j = 2; j < DKW; ++j) suf *= c[j];
    z[0] = suf;
    float pre = c[0];
#pragma unroll
    for (int w = 1; w < DKW; ++w) { pre *= c[w]; z[w] = pre; }
}

// ---------------------------------------------------------------------------
// Projection: fp16 projH [b][s][e] + projT [b][e][s] via LDS-staged transpose.
__global__ __launch_bounds__(256) void proj_f16_kernel(const void* __restrict__ x,
                                                       const void* __restrict__ phi,
                                                       _Float16* __restrict__ projH,
                                                       _Float16* __restrict__ projT) {
    __shared__ int redd[4];
    __shared__ _Float16 zt[EE][40];
    const int tid = threadIdx.x;
    const bool f32 = detect_f32<256>((const u16*)x, tid, redd);

    const int m = blockIdx.x * 256 + tid;  // (b*S + s)*H + h
    float z[DKW];
    proj_compute(x, phi, f32, m, z);

    union { half8v v; _Float16 h[8]; } o;
#pragma unroll
    for (int j = 0; j < DKW; ++j) o.h[j] = (_Float16)z[j];
    *(half8v*)(projH + (size_t)m * DKW) = o.v;

    const int h = m & (HH - 1);
    const int sl = (tid >> 3) & 31;
#pragma unroll
    for (int j = 0; j < DKW; ++j) zt[h * DKW + j][sl] = o.h[j];
    __syncthreads();

    const int b = blockIdx.x >> 5;
    const int s0 = (blockIdx.x * 32) & (SS - 1);
    const int row = tid >> 2, ch = tid & 3;
    half8v vv = *(const half8v*)(&zt[row][ch * 8]);
    *(half8v*)(projT + ((size_t)(b * EE + row)) * SS + s0 + ch * 8) = vv;
}

// ---------------------------------------------------------------------------
// Fused attention, MLP-pipelined: 16 q-rows/block, 512 thr (8 waves),
// grid (S/16, B) = 512 blocks. launch_bounds(512,2) -> VGPR cap 256 so the
// batch-prefetch register arrays below keep 8-16 loads in flight (the R6
// counters showed VGPR=48 serialized every K-loop load at ~400cyc L2 latency).
__device__ __forceinline__ int sidx(int row, int colblk) {
    return row * 1024 + ((colblk ^ (row & 7)) << 3);  // XOR-swizzled 16x1024
}

__global__ __launch_bounds__(512, 2) void fused_attn(const _Float16* __restrict__ projH,
                                                     const _Float16* __restrict__ projT,
                                                     const void* __restrict__ Wp,
                                                     const void* __restrict__ biasp,
                                                     void* __restrict__ outp) {
    __shared__ _Float16 Stile[16 * 1024];          // 32 KB, swizzled
    __shared__ float    pacc[4][16][17];
    __shared__ _Float16 ctx_lds[16][72];
    __shared__ float    rowsum[16];
    __shared__ int      redd[8];

    const int tid = threadIdx.x;
    const int wave = tid >> 6, lane = tid & 63;
    const int lr = lane & 15, quad = lane >> 4;
    const int b = blockIdx.y;
    const int m0 = blockIdx.x * 16;

    const bool f32 = detect_f32<512>((const u16*)Wp, tid, redd);

    const _Float16* Pb = projH + (size_t)b * SS * EE;
    const float scale = 0.35355339059327373f;  // 1/sqrt(DK)

    // ---- phase 1: S = scale * Q . K^T -> Stile. Batch-prefetch 4 iters of
    // B-fragments (8 loads in flight), MFMA group k while group k+1 loads.
    {
        const _Float16* arow = Pb + (size_t)(m0 + lr) * EE;
        half8v a0 = *(const half8v*)(arow + quad * 8);
        half8v a1 = *(const half8v*)(arow + 32 + quad * 8);

        half8v b0[4], b1[4], c0[4], c1[4];
        floatx4 acc[8];
#pragma unroll
        for (int i = 0; i < 4; ++i) {
            const _Float16* brow = Pb + (size_t)(wave * 128 + i * 16 + lr) * EE;
            b0[i] = *(const half8v*)(brow + quad * 8);
            b1[i] = *(const half8v*)(brow + 32 + quad * 8);
        }
#pragma unroll
        for (int i = 0; i < 4; ++i) {
            const _Float16* brow = Pb + (size_t)(wave * 128 + (i + 4) * 16 + lr) * EE;
            c0[i] = *(const half8v*)(brow + quad * 8);
            c1[i] = *(const half8v*)(brow + 32 + quad * 8);
        }
#pragma unroll
        for (int i = 0; i < 4; ++i) {
            acc[i] = floatx4{0.f, 0.f, 0.f, 0.f};
            acc[i] = MFMA16(a0, b0[i], acc[i]);
            acc[i] = MFMA16(a1, b1[i], acc[i]);
        }
#pragma unroll
        for (int i = 0; i < 4; ++i) {
            acc[4 + i] = floatx4{0.f, 0.f, 0.f, 0.f};
            acc[4 + i] = MFMA16(a0, c0[i], acc[4 + i]);
            acc[4 + i] = MFMA16(a1, c1[i], acc[4 + i]);
        }
#pragma unroll
        for (int c = 0; c < 8; ++c) {
#pragma unroll
            for (int r = 0; r < 4; ++r) {
                int row = quad * 4 + r, col = wave * 128 + c * 16 + lr;
                Stile[sidx(row, col >> 3) + (col & 7)] = (_Float16)(acc[c][r] * scale);
            }
        }
    }
    __syncthreads();

    // ---- phase 2: exact softmax (swizzle is a within-row permutation)
    {
        const int row = tid >> 5, seg = tid & 31;
        half8v hv[4];
#pragma unroll
        for (int i = 0; i < 4; ++i)
            hv[i] = *(const half8v*)(&Stile[sidx(row, i * 32 + seg)]);
        float mloc = -1e30f;
#pragma unroll
        for (int i = 0; i < 4; ++i)
#pragma unroll
            for (int j = 0; j < 8; ++j) mloc = fmaxf(mloc, (float)hv[i][j]);
#pragma unroll
        for (int off = 16; off > 0; off >>= 1)
            mloc = fmaxf(mloc, __shfl_xor(mloc, off, 64));
        float lsum = 0.f;
#pragma unroll
        for (int i = 0; i < 4; ++i) {
#pragma unroll
            for (int j = 0; j < 8; ++j) {
                float e = __expf((float)hv[i][j] - mloc);
                lsum += e;
                hv[i][j] = (_Float16)(e * 256.f);  // prescale vs fp16 denormals
            }
        }
#pragma unroll
        for (int off = 16; off > 0; off >>= 1)
            lsum += __shfl_xor(lsum, off, 64);
        if (seg == 0) rowsum[row] = lsum;
#pragma unroll
        for (int i = 0; i < 4; ++i)
            *(half8v*)(&Stile[sidx(row, i * 32 + seg)]) = hv[i];
    }
    __syncthreads();

    // ---- phase 3: ctx = P . V; wave = (khalf = w>>2) x (colg = w&3).
    // Batch-prefetch 4 iters of both LDS A-fragments and global V-fragments.
    const int khalf = wave >> 2, colg = wave & 3;
    floatx4 accT;
    {
        const _Float16* vrow = projT + ((size_t)(b * EE + colg * 16 + lr)) * SS
                               + khalf * 512;
        const int sbase = khalf * 64;  // col-block base for this K-half
        floatx4 acc0 = {0.f, 0.f, 0.f, 0.f};
        floatx4 acc1 = {0.f, 0.f, 0.f, 0.f};

        half8v sA[4], sB[4], vA[4], vB[4];
#pragma unroll
        for (int i = 0; i < 4; ++i) {
            vA[i] = *(const half8v*)(vrow + i * 64 + quad * 8);
            vB[i] = *(const half8v*)(vrow + i * 64 + 32 + quad * 8);
            sA[i] = *(const half8v*)(&Stile[sidx(lr, sbase + i * 8 + quad)]);
            sB[i] = *(const half8v*)(&Stile[sidx(lr, sbase + i * 8 + 4 + quad)]);
        }
        half8v sA2[4], sB2[4], vA2[4], vB2[4];
#pragma unroll
        for (int i = 0; i < 4; ++i) {
            vA2[i] = *(const half8v*)(vrow + 256 + i * 64 + quad * 8);
            vB2[i] = *(const half8v*)(vrow + 256 + i * 64 + 32 + quad * 8);
            sA2[i] = *(const half8v*)(&Stile[sidx(lr, sbase + 32 + i * 8 + quad)]);
            sB2[i] = *(const half8v*)(&Stile[sidx(lr, sbase + 32 + i * 8 + 4 + quad)]);
        }
#pragma unroll
        for (int i = 0; i < 4; ++i) {
            acc0 = MFMA16(sA[i], vA[i], acc0);
            acc1 = MFMA16(sB[i], vB[i], acc1);
        }
#pragma unroll
        for (int i = 0; i < 4; ++i) {
            acc0 = MFMA16(sA2[i], vA2[i], acc0);
            acc1 = MFMA16(sB2[i], vB2[i], acc1);
        }
        accT = acc0 + acc1;
    }
    if (khalf == 1) {
#pragma unroll
        for (int r = 0; r < 4; ++r) pacc[colg][quad * 4 + r][lr] = accT[r];
    }
    __syncthreads();
    if (khalf == 0) {
#pragma unroll
        for (int r = 0; r < 4; ++r) {
            int row_l = quad * 4 + r;
            float inv = 1.0f / (256.0f * rowsum[row_l]);
            ctx_lds[row_l][colg * 16 + lr] =
                (_Float16)((accT[r] + pacc[colg][row_l][lr]) * inv);
        }
    }
    __syncthreads();

    // ---- phase 4: out = ctx @ W^T + bias (waves 0-3)
    if (wave < 4) {
        const int o = wave * 16 + lr;
        half8v ca0 = *(const half8v*)(&ctx_lds[lr][quad * 8]);
        half8v ca1 = *(const half8v*)(&ctx_lds[lr][32 + quad * 8]);
        half8v wb0, wb1;
        if (f32) {
            const float* wr = (const float*)Wp + (size_t)o * EE;
            union { half8v v; _Float16 h[8]; } w0, w1;
#pragma unroll
            for (int j = 0; j < 8; ++j) {
                w0.h[j] = (_Float16)wr[quad * 8 + j];
                w1.h[j] = (_Float16)wr[32 + quad * 8 + j];
            }
            wb0 = w0.v; wb1 = w1.v;
        } else {
            const bf16* wr = (const bf16*)Wp + (size_t)o * EE;
            union { uint4 u; bf16 hv[8]; } r0, r1;
            r0.u = *(const uint4*)(wr + quad * 8);
            r1.u = *(const uint4*)(wr + 32 + quad * 8);
            union { half8v v; _Float16 h[8]; } w0, w1;
#pragma unroll
            for (int j = 0; j < 8; ++j) {
                w0.h[j] = (_Float16)__bfloat162float(r0.hv[j]);
                w1.h[j] = (_Float16)__bfloat162float(r1.hv[j]);
            }
            wb0 = w0.v; wb1 = w1.v;
        }
        floatx4 oacc = {0.f, 0.f, 0.f, 0.f};
        oacc = MFMA16(ca0, wb0, oacc);
        oacc = MFMA16(ca1, wb1, oacc);

        float bo = f32 ? ((const float*)biasp)[o]
                       : __bfloat162float(((const bf16*)biasp)[o]);
#pragma unroll
        for (int r = 0; r < 4; ++r) {
            size_t oi = ((size_t)b * SS + m0 + quad * 4 + r) * EE + o;
            float val = oacc[r] + bo;
            if (f32) ((float*)outp)[oi] = val;
            else     ((bf16*)outp)[oi] = __float2bfloat16(val);
        }
    }
}

// ---------------------------------------------------------------------------
extern "C" void kernel_launch(void* const* d_in, const int* in_sizes, int n_in,
                              void* d_out, int out_size, void* d_ws, size_t ws_size,
                              hipStream_t stream) {
    const void* x    = d_in[0];
    const void* phi  = d_in[1];
    const void* W    = d_in[2];
    const void* bias = d_in[3];

    _Float16* projH = (_Float16*)d_ws;
    _Float16* projT = (_Float16*)((char*)d_ws + OFF_PROJT);

    proj_f16_kernel<<<dim3(BB * SS * HH / 256), dim3(256), 0, stream>>>(x, phi, projH, projT);
    fused_attn<<<dim3(SS / 16, BB), dim3(512), 0, stream>>>(projH, projT, W, bias, d_out);
}